// Round 10
// baseline (83.055 us; speedup 1.0000x reference)
//
#include <hip/hip_runtime.h>
#include <hip/hip_bf16.h>
#include <math.h>

#define N_NODE 50000
#define N_MOL  1024
#define C_DIM  128
#define P_DIM  64
#define M_DIM  128
#define NM_REM 848   // N_NODE % N_MOL: mols < NM_REM have 49 nodes, rest 48
#define NVBLK  196   // ceil(N_NODE/256) verify blocks

typedef __attribute__((ext_vector_type(8))) short bf16x8;
typedef __attribute__((ext_vector_type(4))) float f32x4;

static __device__ __forceinline__ short f2bf(float x) {
    __hip_bfloat16 h = __float2bfloat16(x);
    return *reinterpret_cast<short*>(&h);
}
static __device__ __forceinline__ float bfs2f(short s) {
    unsigned int u = ((unsigned int)(unsigned short)s) << 16;
    float f;
    __builtin_memcpy(&f, &u, 4);
    return f;
}
static __device__ __forceinline__ int off_of(int m) {
    return (m < NM_REM) ? 49 * m : NM_REM + 48 * m;
}

// ---------------------------------------------------------------------------
// K1: prep tables + verify the i%1024 one-hot guess + closed-form list/offsets.
__global__ __launch_bounds__(256) void k_prep_guess(const float* __restrict__ mat,
                                                    const float* __restrict__ map_W,
                                                    const float* __restrict__ att_W,
                                                    const float* __restrict__ Wih,
                                                    const float* __restrict__ Whh,
                                                    const float* __restrict__ alignW,
                                                    short* __restrict__ Bbf,
                                                    short* __restrict__ Wihb,
                                                    short* __restrict__ Whhb,
                                                    int* __restrict__ list,
                                                    int* __restrict__ offsets,
                                                    int* __restrict__ flags) {
    const int NB = 272 * 192;
    const int NW = 384 * 128;
    int idx = blockIdx.x * 256 + threadIdx.x;
    if (idx < NB) {
        int r = idx / 192, k = idx - r * 192;
        float v = 0.f;
        if (r < 128) { if (k < 128) v = map_W[r * 128 + k]; }
        else if (r < 256) v = att_W[(size_t)(r - 128) * 192 + k];
        else if (r == 256) v = (k < 128) ? alignW[192 + k] : alignW[k];
        Bbf[idx] = f2bf(v);
    } else if (idx < NB + NW) {
        int j = idx - NB;
        Wihb[j] = f2bf(Wih[j]);
    } else if (idx < NB + 2 * NW) {
        int j = idx - NB - NW;
        Whhb[j] = f2bf(Whh[j]);
    }
    if (idx <= N_MOL) offsets[idx] = off_of(idx);
    if (idx < N_NODE) {
        int m = idx & (N_MOL - 1);
        list[off_of(m) + (idx >> 10)] = idx;
    }
    if (blockIdx.x < NVBLK) {
        __shared__ int s_bad;
        if (threadIdx.x == 0) s_bad = 0;
        __syncthreads();
        if (idx < N_NODE) {
            int m = idx & (N_MOL - 1);
            if (!(mat[(size_t)m * N_NODE + idx] > 0.5f)) atomicOr(&s_bad, 1);
        }
        __syncthreads();
        if (threadIdx.x == 0) flags[blockIdx.x] = s_bad;
    }
}

// K2: if any flag set, rebuild assign/offsets/list in one block (never taken
// on canonical input).
__global__ __launch_bounds__(1024) void k_fallback(const float4* __restrict__ mat4,
                                                   const int* __restrict__ flags,
                                                   int* __restrict__ assign,
                                                   int* __restrict__ offsets,
                                                   int* __restrict__ list) {
    __shared__ int s_any;
    __shared__ int s_scan[N_MOL];
    __shared__ int s_tile[4096];
    int t = threadIdx.x;
    if (t == 0) s_any = 0;
    __syncthreads();
    if (t < NVBLK && flags[t]) atomicOr(&s_any, 1);
    __syncthreads();
    if (s_any == 0) return;

    const int total4 = (N_MOL * N_NODE) / 4;
    for (int j = t; j < total4; j += 1024) {
        float4 v = mat4[j];
        float f[4] = {v.x, v.y, v.z, v.w};
#pragma unroll
        for (int c = 0; c < 4; ++c) {
            if (f[c] > 0.5f) {
                int idx = j * 4 + c;
                int m = idx / N_NODE;
                assign[idx - m * N_NODE] = m;
            }
        }
    }
    __syncthreads();
    s_scan[t] = 0;
    __syncthreads();
    for (int i = t; i < N_NODE; i += 1024) atomicAdd(&s_scan[assign[i]], 1);
    __syncthreads();
    for (int d = 1; d < N_MOL; d <<= 1) {
        int v = (t >= d) ? s_scan[t - d] : 0;
        __syncthreads();
        s_scan[t] += v;
        __syncthreads();
    }
    offsets[t + 1] = s_scan[t];
    if (t == 0) offsets[0] = 0;
    int base_off = (t == 0) ? 0 : s_scan[t - 1];
    __syncthreads();
    int cur = 0;
    for (int tb = 0; tb < N_NODE; tb += 4096) {
        for (int q = t; q < 4096; q += 1024)
            s_tile[q] = (tb + q < N_NODE) ? assign[tb + q] : -1;
        __syncthreads();
        int lim = (N_NODE - tb < 4096) ? (N_NODE - tb) : 4096;
        for (int q = 0; q < lim; ++q)
            if (s_tile[q] == t) list[base_off + (cur++)] = tb + q;
        __syncthreads();
    }
}

// K3: fused MFMA GEMM over PERMUTED rows. mapped columns (0..127) are reduced
// to per-molecule partial segment sums IN-KERNEL (2-slot deterministic) and
// never stored; hbuf columns staged in LDS then 16B vector stores.
__global__ __launch_bounds__(256) void k_gemm_fused(const float* __restrict__ node,
                                                    const float* __restrict__ pos,
                                                    const int* __restrict__ list,
                                                    const int* __restrict__ offsets,
                                                    const short* __restrict__ Bbf,
                                                    const float* __restrict__ map_b,
                                                    const float* __restrict__ att_b,
                                                    __hip_bfloat16* __restrict__ hbuf,
                                                    float* __restrict__ sbase,
                                                    float* __restrict__ molpart) {
    __shared__ short smem[64 * 264];   // staging (stride 264) then out-tile
    __shared__ int s_list[64];
    __shared__ int s_mid[64];
    int t = threadIdx.x;
    int n0 = blockIdx.x * 64;

    if (t < 64) {
        int pr = n0 + t;
        int mid = -1;
        s_list[t] = 0;
        if (pr < N_NODE) {
            s_list[t] = list[pr];
            // molecule of permuted row pr: closed-form guess, verify, else bsearch
            int mg = (pr < 49 * NM_REM) ? pr / 49 : (pr - NM_REM) / 48;
            if (offsets[mg] <= pr && pr < offsets[mg + 1]) mid = mg;
            else {
                int lo = 0, hi = N_MOL - 1;
                while (lo < hi) {
                    int mm = (lo + hi + 1) >> 1;
                    if (offsets[mm] <= pr) lo = mm; else hi = mm - 1;
                }
                mid = lo;
            }
        }
        s_mid[t] = mid;
    }
    __syncthreads();

    // stage A: 64 rows x 192 k (fp32 -> bf16), stride 264 shorts
    for (int idx = t; idx < 64 * 48; idx += 256) {
        int row = idx / 48;
        int c4 = idx - row * 48;
        float4 v = make_float4(0.f, 0.f, 0.f, 0.f);
        if (n0 + row < N_NODE) {
            int id = s_list[row];
            if (c4 < 32) v = *(const float4*)&node[(size_t)id * C_DIM + c4 * 4];
            else         v = *(const float4*)&pos[(size_t)id * P_DIM + (c4 - 32) * 4];
        }
        ushort4 u;
        u.x = (unsigned short)f2bf(v.x);
        u.y = (unsigned short)f2bf(v.y);
        u.z = (unsigned short)f2bf(v.z);
        u.w = (unsigned short)f2bf(v.w);
        *(ushort4*)&smem[row * 264 + c4 * 4] = u;
    }
    __syncthreads();

    int wid = t >> 6, lane = t & 63;
    int wr = wid >> 1, wc = wid & 1;
    int lrow = lane & 15, lk = (lane >> 4) * 8;

    bf16x8 a[2][6];
#pragma unroll
    for (int mt = 0; mt < 2; ++mt)
#pragma unroll
        for (int k = 0; k < 6; ++k)
            a[mt][k] = *(const bf16x8*)&smem[(wr * 32 + mt * 16 + lrow) * 264 + k * 32 + lk];

    f32x4 acc[2][9] = {};
#pragma unroll
    for (int ct = 0; ct < 9; ++ct) {
        if (ct == 8 && wc == 0) break;   // sbase tile computed by wc==1 only
        int c0 = wc * 128 + ct * 16;
        bf16x8 b[6];
#pragma unroll
        for (int k = 0; k < 6; ++k)
            b[k] = *(const bf16x8*)&Bbf[(size_t)(c0 + lrow) * 192 + k * 32 + lk];
#pragma unroll
        for (int mt = 0; mt < 2; ++mt)
#pragma unroll
            for (int k = 0; k < 6; ++k)
                acc[mt][ct] = __builtin_amdgcn_mfma_f32_16x16x32_bf16(
                    a[mt][k], b[k], acc[mt][ct], 0, 0, 0);
    }

    __syncthreads();   // all waves done reading staged A; smem becomes out-tile

    // bias + activation -> bf16 out-tile [row][col 0..255], stride 264
#pragma unroll
    for (int ct = 0; ct < 8; ++ct) {
        int c = wc * 128 + ct * 16 + lrow;
        float bias = (c < 128) ? map_b[c] : att_b[c - 128];
#pragma unroll
        for (int mt = 0; mt < 2; ++mt) {
#pragma unroll
            for (int r = 0; r < 4; ++r) {
                int row = wr * 32 + mt * 16 + (lane >> 4) * 4 + r;
                float v = acc[mt][ct][r] + bias;
                if (c < 128) v = (v > 0.f) ? v : 0.01f * v;
                smem[row * 264 + c] = f2bf(v);
            }
        }
    }
    if (wc == 1 && lrow == 0) {
#pragma unroll
        for (int mt = 0; mt < 2; ++mt)
#pragma unroll
            for (int r = 0; r < 4; ++r) {
                int pr = n0 + wr * 32 + mt * 16 + (lane >> 4) * 4 + r;
                if (pr < N_NODE) sbase[pr] = acc[mt][8][r];
            }
    }
    __syncthreads();

    // vectorized hbuf readout (cols 128..255 only)
    short* hp = (short*)hbuf;
    for (int v = t; v < 64 * 16; v += 256) {
        int row = v >> 4, ch = v & 15;
        int pr = n0 + row;
        if (pr < N_NODE)
            *(bf16x8*)&hp[(size_t)pr * 128 + ch * 8] =
                *(const bf16x8*)&smem[row * 264 + 128 + ch * 8];
    }

    // per-molecule partial segsum of mapped cols (t<128 -> col t).
    // Block's rows span <=3 molecules; slot0 = head-block, slot1 = tail-block.
    if (t < 128) {
        int col = t;
        float acc2 = 0.f;
        int cur = s_mid[0];
        for (int row = 0; row < 64; ++row) {
            int m = s_mid[row];
            if (m < 0) break;
            if (m != cur) {
                int offm = offsets[cur];
                int slot = (offm >= n0) ? 0 : 1;
                molpart[slot * (N_MOL * 128) + cur * 128 + col] = acc2;
                if (slot == 0 && offsets[cur + 1] <= n0 + 64)
                    molpart[N_MOL * 128 + cur * 128 + col] = 0.f;
                acc2 = 0.f;
                cur = m;
            }
            acc2 += bfs2f(smem[row * 264 + col]);
        }
        if (cur >= 0) {
            int offm = offsets[cur];
            int slot = (offm >= n0) ? 0 : 1;
            molpart[slot * (N_MOL * 128) + cur * 128 + col] = acc2;
            if (slot == 0 && offsets[cur + 1] <= n0 + 64)
                molpart[N_MOL * 128 + cur * 128 + col] = 0.f;
        }
    }
}

// K4: fused radius iterations, 4 mols/block (256 blocks). mol0 comes from
// molpart (2-slot add). h rows cached in LDS during iter 0; iter 1 reads LDS.
__global__ __launch_bounds__(256) void k_molrad(const __hip_bfloat16* __restrict__ hbuf,
                                                const float* __restrict__ sbase,
                                                const float* __restrict__ molpart,
                                                const float* __restrict__ alignW,
                                                const float* __restrict__ alignb,
                                                const short* __restrict__ Wihb,
                                                const short* __restrict__ Whhb,
                                                const float* __restrict__ bih,
                                                const float* __restrict__ bhh,
                                                const int* __restrict__ offsets,
                                                float* __restrict__ mol) {
    __shared__ short s_actx[16][136];   // rows 0-3 = ctx, 4-15 zero
    __shared__ short s_amol[16][136];   // rows 0-3 = mol (bf16), 4-15 zero
    __shared__ float s_molf[4][128];
    __shared__ short s_hc[4][64 * 128]; // per-wave h-row cache (65.5 KB)
    int t = threadIdx.x;
    int w = t >> 6, lane = t & 63;
    int m0 = blockIdx.x * 4;
    int mymol = m0 + w;

    for (int i = t; i < 12 * 128; i += 256) {
        int r = 4 + (i >> 7), c = i & 127;
        s_actx[r][c] = 0;
        s_amol[r][c] = 0;
    }

    int off = offsets[mymol];
    int cnt = offsets[mymol + 1] - off;   // <= 64 on canonical input
    int Q = cnt * 16;

    // mol0 from the two deterministic partial-sum slots
    {
        float a0 = molpart[(size_t)mymol * 128 + lane]
                 + molpart[(size_t)N_MOL * 128 + (size_t)mymol * 128 + lane];
        float a1 = molpart[(size_t)mymol * 128 + 64 + lane]
                 + molpart[(size_t)N_MOL * 128 + (size_t)mymol * 128 + 64 + lane];
        s_molf[w][lane] = a0;
        s_molf[w][64 + lane] = a1;
        s_amol[w][lane] = f2bf(a0);
        s_amol[w][64 + lane] = f2bf(a1);
    }
    float aw0 = alignW[lane], aw1 = alignW[64 + lane];
    float ab = alignb[0];
    int lrow = lane & 15, lk = (lane >> 4) * 8;
    __syncthreads();

    for (int it = 0; it < 2; ++it) {
        // dm = mol . alignW[0:128] + b (wave-local, reads own row w)
        float v = s_molf[w][lane] * aw0 + s_molf[w][64 + lane] * aw1;
#pragma unroll
        for (int d = 32; d > 0; d >>= 1) v += __shfl_xor(v, d);
        float dm = v + ab;

        // scores + softmax (wave-local)
        float x = -1e30f;
        if (lane < cnt) {
            x = sbase[off + lane] + dm;
            x = (x > 0.f) ? x : 0.01f * x;
        }
        float mx = x;
#pragma unroll
        for (int d = 32; d > 0; d >>= 1) mx = fmaxf(mx, __shfl_xor(mx, d));
        float e = (lane < cnt) ? __expf(x - mx) : 0.f;
        float sm = e;
#pragma unroll
        for (int d = 32; d > 0; d >>= 1) sm += __shfl_xor(sm, d);
        float myw = e / sm;

        // ctx = sum_i w_i h_i; iter 0 streams global + fills LDS cache,
        // iter 1 reads the wave-local LDS cache.
        float c8[8] = {};
        if (it == 0) {
            const short* hb = (const short*)hbuf + (size_t)off * 128;
            for (int q = lane; q < Q; q += 64) {
                bf16x8 vv = *(const bf16x8*)&hb[q * 8];
                *(bf16x8*)&s_hc[w][q * 8] = vv;
                float wgt = __shfl(myw, q >> 4);
#pragma unroll
                for (int jj = 0; jj < 8; ++jj) c8[jj] += wgt * bfs2f(vv[jj]);
            }
        } else {
            for (int q = lane; q < Q; q += 64) {
                bf16x8 vv = *(const bf16x8*)&s_hc[w][q * 8];
                float wgt = __shfl(myw, q >> 4);
#pragma unroll
                for (int jj = 0; jj < 8; ++jj) c8[jj] += wgt * bfs2f(vv[jj]);
            }
        }
#pragma unroll
        for (int jj = 0; jj < 8; ++jj) {
            c8[jj] += __shfl_xor(c8[jj], 16);
            c8[jj] += __shfl_xor(c8[jj], 32);
        }
        if (lane < 16) {
#pragma unroll
            for (int jj = 0; jj < 8; ++jj) {
                float cv = c8[jj];
                cv = (cv > 0.f) ? cv : (__expf(cv) - 1.f);
                s_actx[w][lane * 8 + jj] = f2bf(cv);
            }
        }
        __syncthreads();   // all ctx staged; s_molf dm-reads done

        // GRU MFMA: wave w covers chans [w*32, w*32+32) for r,z,n gates.
        bf16x8 a_c[4], a_m[4];
#pragma unroll
        for (int k = 0; k < 4; ++k) {
            a_c[k] = *(const bf16x8*)&s_actx[lrow][k * 32 + lk];
            a_m[k] = *(const bf16x8*)&s_amol[lrow][k * 32 + lk];
        }
        f32x4 ai[6], ah[6];
#pragma unroll
        for (int j = 0; j < 6; ++j) { ai[j] = (f32x4){}; ah[j] = (f32x4){}; }
#pragma unroll
        for (int j = 0; j < 6; ++j) {
            int c0 = w * 32 + (j & 1) * 16 + (j >> 1) * 128;
#pragma unroll
            for (int k = 0; k < 4; ++k) {
                bf16x8 bi = *(const bf16x8*)&Wihb[(size_t)(c0 + lrow) * 128 + k * 32 + lk];
                ai[j] = __builtin_amdgcn_mfma_f32_16x16x32_bf16(a_c[k], bi, ai[j], 0, 0, 0);
                bf16x8 bh = *(const bf16x8*)&Whhb[(size_t)(c0 + lrow) * 128 + k * 32 + lk];
                ah[j] = __builtin_amdgcn_mfma_f32_16x16x32_bf16(a_m[k], bh, ah[j], 0, 0, 0);
            }
        }
        __syncthreads();   // all waves' LDS reads done before gate writes

        // gate math fully in-register: lanes 0-15 hold rows 0-3 (4 mols)
        if (lane < 16) {
#pragma unroll
            for (int j2 = 0; j2 < 2; ++j2) {
                int chan = w * 32 + j2 * 16 + lane;
                float br = bih[chan], bz = bih[128 + chan], bn = bih[256 + chan];
                float cr = bhh[chan], cz = bhh[128 + chan], cn = bhh[256 + chan];
#pragma unroll
                for (int r = 0; r < 4; ++r) {
                    float gir = ai[j2][r] + br;
                    float giz = ai[2 + j2][r] + bz;
                    float gin = ai[4 + j2][r] + bn;
                    float ghr = ah[j2][r] + cr;
                    float ghz = ah[2 + j2][r] + cz;
                    float ghn = ah[4 + j2][r] + cn;
                    float molc = s_molf[r][chan];
                    float rr = 1.f / (1.f + __expf(-(gir + ghr)));
                    float zz = 1.f / (1.f + __expf(-(giz + ghz)));
                    float nn = tanhf(gin + rr * ghn);
                    float o = fmaxf((1.f - zz) * nn + zz * molc, 0.f);
                    s_molf[r][chan] = o;
                    s_amol[r][chan] = f2bf(o);
                }
            }
        }
        __syncthreads();   // gates visible for next iter / final write
    }

#pragma unroll
    for (int j = 0; j < 2; ++j) {
        int item = t + j * 256;
        int mm = item >> 7, c = item & 127;
        mol[(size_t)(m0 + mm) * 128 + c] = s_molf[mm][c];
    }
}

extern "C" void kernel_launch(void* const* d_in, const int* in_sizes, int n_in,
                              void* d_out, int out_size, void* d_ws, size_t ws_size,
                              hipStream_t stream) {
    const float* node   = (const float*)d_in[0];
    const float* pos    = (const float*)d_in[1];
    const float* mat    = (const float*)d_in[2];
    const float* map_W  = (const float*)d_in[4];
    const float* map_b  = (const float*)d_in[5];
    const float* att_W  = (const float*)d_in[6];
    const float* att_b  = (const float*)d_in[7];
    const float* alignW = (const float*)d_in[8];
    const float* alignb = (const float*)d_in[9];
    const float* gWih   = (const float*)d_in[10];
    const float* gWhh   = (const float*)d_in[11];
    const float* gbih   = (const float*)d_in[12];
    const float* gbhh   = (const float*)d_in[13];
    float* mol = (float*)d_out;   // [1024,128]

    size_t o = 0;
    auto alloc = [&](size_t bytes) { size_t r = o; o += (bytes + 255) & ~(size_t)255; return r; };
    char* ws = (char*)d_ws;
    int*   flags   = (int*)(ws + alloc((size_t)NVBLK * 4));
    int*   assign  = (int*)(ws + alloc((size_t)N_NODE * 4));
    int*   offsets = (int*)(ws + alloc((size_t)(N_MOL + 1) * 4));
    int*   list    = (int*)(ws + alloc((size_t)N_NODE * 4));
    short* Bbf     = (short*)(ws + alloc((size_t)272 * 192 * 2));
    short* Wihb    = (short*)(ws + alloc((size_t)384 * 128 * 2));
    short* Whhb    = (short*)(ws + alloc((size_t)384 * 128 * 2));
    __hip_bfloat16* hbuf = (__hip_bfloat16*)(ws + alloc((size_t)N_NODE * 128 * 2));
    float* sbase   = (float*)(ws + alloc((size_t)N_NODE * 4));
    float* molpart = (float*)(ws + alloc((size_t)2 * N_MOL * 128 * 4));

    int prep_items = 272 * 192 + 2 * 384 * 128;
    k_prep_guess<<<(prep_items + 255) / 256, 256, 0, stream>>>(
        mat, map_W, att_W, gWih, gWhh, alignW, Bbf, Wihb, Whhb, list, offsets, flags);
    k_fallback<<<1, 1024, 0, stream>>>((const float4*)mat, flags,
                                       assign, offsets, list);
    k_gemm_fused<<<(N_NODE + 63) / 64, 256, 0, stream>>>(node, pos, list, offsets, Bbf,
                                                         map_b, att_b,
                                                         hbuf, sbase, molpart);
    k_molrad<<<N_MOL / 4, 256, 0, stream>>>(hbuf, sbase, molpart, alignW, alignb,
                                            Wihb, Whhb, gbih, gbhh, offsets, mol);
}